// Round 6
// baseline (542.934 us; speedup 1.0000x reference)
//
#include <hip/hip_runtime.h>

#define IMG_H  2048
#define IMG_W  2048
#define IMG_C  8
#define IMG_WF (IMG_W * IMG_C)          // floats per image row = 16384

#define TILE   32                       // 32x32-pixel tiles
#define TB     (IMG_H / TILE)           // 64 tiles per dim
#define KBINS  (TB * TB)                // 4096 bins
#define TLR    (TILE + 1)               // 33 tile rows (halo)
#define TLC    ((TILE + 1) * IMG_C)     // 264 floats per tile row (halo col)
#define TLF4   (TLR * (TLC / 4))        // 2178 float4 per tile

#define SBLOCK 512
#define SPT    32
#define GBLOCK 256

// ---------------------------------------------------------------------------
// Interp math, must match reference op order exactly:
//   c = max(coord - bias, 0); low = min(floor(c), H-2); d = c - low
//   mb = br + d0*(bl-br); mt = tr + d0*(tl-tr); out = mb + d1*(mt-mb)
// (tl = [i0,i1], tr = [i0+1,i1], bl = [i0,i1+1], br = [i0+1,i1+1])
// ---------------------------------------------------------------------------
__device__ __forceinline__ float4 lerp4(float4 tl, float4 tr, float4 bl, float4 br,
                                        float d0, float d1) {
    float4 o;
    float mb, mt;
    mb = br.x + d0 * (bl.x - br.x); mt = tr.x + d0 * (tl.x - tr.x); o.x = mb + d1 * (mt - mb);
    mb = br.y + d0 * (bl.y - br.y); mt = tr.y + d0 * (tl.y - tr.y); o.y = mb + d1 * (mt - mb);
    mb = br.z + d0 * (bl.z - br.z); mt = tr.z + d0 * (tl.z - tr.z); o.z = mb + d1 * (mt - mb);
    mb = br.w + d0 * (bl.w - br.w); mt = tr.w + d0 * (tl.w - tr.w); o.w = mb + d1 * (mt - mb);
    return o;
}

// 2D tile bin. Uses the SAME clamp math as the interp, so scatter and
// gather derive bit-identical (i0,i1) from the stored coords.
__device__ __forceinline__ int bin2d(float cx, float cy, float b0, float b1) {
    float c0 = fmaxf(cx - b0, 0.0f);
    float c1 = fmaxf(cy - b1, 0.0f);
    float low0 = fminf(floorf(c0), (float)(IMG_H - 2));
    float low1 = fminf(floorf(c1), (float)(IMG_W - 2));
    return ((int)low0 >> 5) * TB + ((int)low1 >> 5);
}

// ---------------------------------------------------------------------------
// Pass 1: bin samples by 32x32 tile. LDS histogram -> chunk reservation
// (1 global atomic per non-empty bin per block) -> scatter (s,x,y) SoA.
// Overflow (>cap in a bin; ~0.1% at 1.5-sigma margin) is computed directly
// here -> correctness never depends on capacity.
// ---------------------------------------------------------------------------
__global__ __launch_bounds__(SBLOCK) void scatter_kernel(
    const float* __restrict__ coords,
    const float* __restrict__ visible,
    const float* __restrict__ bias,
    float* __restrict__ out,
    unsigned* __restrict__ cursor,     // [KBINS]
    unsigned* __restrict__ recIdx,     // [KBINS*cap]
    float* __restrict__ recX,
    float* __restrict__ recY,
    int n, unsigned cap)
{
    __shared__ unsigned hist[KBINS];   // 16 KB
    __shared__ unsigned basev[KBINS];  // 16 KB
    __shared__ unsigned lofs[KBINS];   // 16 KB

    int t = threadIdx.x;
    for (int u = t; u < KBINS; u += SBLOCK) hist[u] = 0;
    __syncthreads();

    long long blockStart = (long long)blockIdx.x * (SBLOCK * SPT);
    float b0 = bias[0];
    float b1 = bias[1];

    // phase 1: LDS histogram (coalesced coords reads)
    for (int k = 0; k < SPT; ++k) {
        long long s = blockStart + (long long)k * SBLOCK + t;
        if (s < n) {
            float2 cv = *(const float2*)(coords + 2 * (size_t)s);
            atomicAdd(&hist[bin2d(cv.x, cv.y, b0, b1)], 1u);
        }
    }
    __syncthreads();

    // phase 2: reserve a contiguous chunk per bin
    for (int u = t; u < KBINS; u += SBLOCK) {
        unsigned h = hist[u];
        basev[u] = h ? atomicAdd(&cursor[u], h) : 0u;
        lofs[u] = 0;
    }
    __syncthreads();

    // phase 3: scatter records (coords re-read, L2-hot)
    for (int k = 0; k < SPT; ++k) {
        long long s = blockStart + (long long)k * SBLOCK + t;
        if (s < n) {
            float2 cv = *(const float2*)(coords + 2 * (size_t)s);
            int b = bin2d(cv.x, cv.y, b0, b1);
            unsigned off = atomicAdd(&lofs[b], 1u);
            unsigned slot = basev[b] + off;
            if (slot < cap) {
                size_t g = (size_t)b * cap + slot;
                recIdx[g] = (unsigned)s;
                recX[g] = cv.x;
                recY[g] = cv.y;
            } else {
                // Overflow: compute this sample directly (rare).
                float c0 = fmaxf(cv.x - b0, 0.0f);
                float c1 = fmaxf(cv.y - b1, 0.0f);
                float low0 = fminf(floorf(c0), (float)(IMG_H - 2));
                float low1 = fminf(floorf(c1), (float)(IMG_W - 2));
                float d0 = c0 - low0;
                float d1 = c1 - low1;
                int i0 = (int)low0;
                int i1 = (int)low1;
                const float* pt = visible + ((size_t)i0 * IMG_W + (size_t)i1) * IMG_C;
                const float* pb = pt + (size_t)IMG_W * IMG_C;
                for (int q = 0; q < 2; ++q) {
                    float4 tl = *(const float4*)(pt + 4 * q);
                    float4 bl = *(const float4*)(pt + 8 + 4 * q);
                    float4 tr = *(const float4*)(pb + 4 * q);
                    float4 br = *(const float4*)(pb + 8 + 4 * q);
                    float4 o = lerp4(tl, tr, bl, br, d0, d1);
                    *(float4*)(out + (size_t)s * IMG_C + 4 * q) = o;
                }
            }
        }
    }
}

// ---------------------------------------------------------------------------
// Pass 2: one block per tile-bin. Stage the 33x33-pixel tile (34.8 KB) in
// LDS -- each visible byte is read from HBM exactly once, immune to cache
// eviction -- then serve all of the bin's samples from LDS. One thread per
// sample (all 8 channels); out-writes are scattered 32 B granules, which
// measured at zero write amplification (R3: WRITE_SIZE == ideal).
// ---------------------------------------------------------------------------
__global__ __launch_bounds__(GBLOCK) void gather_tile_kernel(
    const float* __restrict__ bias,
    const float* __restrict__ visible,
    const unsigned* __restrict__ cursor,   // fill counts per bin
    const unsigned* __restrict__ recIdx,
    const float* __restrict__ recX,
    const float* __restrict__ recY,
    float* __restrict__ out,
    unsigned cap)
{
    __shared__ float tile[TLR * TLC];      // 33*264 floats = 34848 B

    int b  = blockIdx.x;                   // bin id 0..4095
    int bh = b >> 6;                       // tile row
    int bw = b & (TB - 1);                 // tile col
    int r0  = bh * TILE;                   // first image row of tile
    int c0f = bw * TILE * IMG_C;           // first float within image row

    int t = threadIdx.x;

    // Stage tile + halo. Edge tiles: clamp source (clamped cells never read,
    // since i0<=H-2, i1<=W-2 -> local idx <= 30, +1 halo <= 31 < 32).
    for (int v = t; v < TLF4; v += GBLOCK) {
        int trow = v / (TLC / 4);          // 0..32
        int tc4  = v - trow * (TLC / 4);   // 0..65
        int gr = r0 + trow;  if (gr > IMG_H - 1) gr = IMG_H - 1;
        int gf = c0f + tc4 * 4; if (gf > IMG_WF - 4) gf = IMG_WF - 4;
        *(float4*)(&tile[trow * TLC + tc4 * 4]) =
            *(const float4*)(visible + (size_t)gr * IMG_WF + gf);
    }
    __syncthreads();

    float b0 = bias[0];
    float b1 = bias[1];

    unsigned cnt = cursor[b];
    if (cnt > cap) cnt = cap;
    size_t base = (size_t)b * cap;

    for (unsigned j = t; j < cnt; j += GBLOCK) {
        unsigned s = recIdx[base + j];
        float cx = recX[base + j];
        float cy = recY[base + j];

        float cc0 = fmaxf(cx - b0, 0.0f);
        float cc1 = fmaxf(cy - b1, 0.0f);
        float low0 = fminf(floorf(cc0), (float)(IMG_H - 2));
        float low1 = fminf(floorf(cc1), (float)(IMG_W - 2));
        float d0 = cc0 - low0;
        float d1 = cc1 - low1;
        int lr  = (int)low0 - r0;                // 0..31 by bin construction
        int lcf = (int)low1 * IMG_C - c0f;       // 0..248, multiple of 8

        const float* q_t = &tile[lr * TLC + lcf];
        const float* q_b = q_t + TLC;

        float4 tl0 = *(const float4*)(q_t);
        float4 bl0 = *(const float4*)(q_t + IMG_C);
        float4 tr0 = *(const float4*)(q_b);
        float4 br0 = *(const float4*)(q_b + IMG_C);
        float4 o0 = lerp4(tl0, tr0, bl0, br0, d0, d1);

        float4 tl1 = *(const float4*)(q_t + 4);
        float4 bl1 = *(const float4*)(q_t + IMG_C + 4);
        float4 tr1 = *(const float4*)(q_b + 4);
        float4 br1 = *(const float4*)(q_b + IMG_C + 4);
        float4 o1 = lerp4(tl1, tr1, bl1, br1, d0, d1);

        *(float4*)(out + (size_t)s * IMG_C)     = o0;
        *(float4*)(out + (size_t)s * IMG_C + 4) = o1;
    }
}

// ---------------------------------------------------------------------------
// Fallback (ws too small): proven single-pass kernel (R0/R2, 228 us).
// ---------------------------------------------------------------------------
__global__ __launch_bounds__(256) void idx2pixel_simple(
    const float* __restrict__ coords,
    const float* __restrict__ visible,
    const float* __restrict__ bias,
    float* __restrict__ out,
    int n)
{
    int tid = blockIdx.x * blockDim.x + threadIdx.x;
    int s = tid >> 1;
    int part = tid & 1;
    if (s >= n) return;

    float2 cv = *(const float2*)(coords + 2 * (size_t)s);
    float b0 = bias[0];
    float b1 = bias[1];

    float c0 = fmaxf(cv.x - b0, 0.0f);
    float c1 = fmaxf(cv.y - b1, 0.0f);
    float low0 = fminf(floorf(c0), (float)(IMG_H - 2));
    float low1 = fminf(floorf(c1), (float)(IMG_W - 2));
    float d0 = c0 - low0;
    float d1 = c1 - low1;
    int i0 = (int)low0;
    int i1 = (int)low1;

    const float* p_t = visible + ((size_t)i0 * IMG_W + (size_t)i1) * IMG_C + part * 4;
    const float* p_b = p_t + (size_t)IMG_W * IMG_C;

    float4 tl = *(const float4*)(p_t);
    float4 bl = *(const float4*)(p_t + 8);
    float4 tr = *(const float4*)(p_b);
    float4 br = *(const float4*)(p_b + 8);

    float4 o = lerp4(tl, tr, bl, br, d0, d1);
    *(float4*)(out + (size_t)s * IMG_C + part * 4) = o;
}

extern "C" void kernel_launch(void* const* d_in, const int* in_sizes, int n_in,
                              void* d_out, int out_size, void* d_ws, size_t ws_size,
                              hipStream_t stream) {
    const float* coords  = (const float*)d_in[0];   // (N, 2) f32
    const float* visible = (const float*)d_in[1];   // (H, W, C) f32
    const float* bias    = (const float*)d_in[2];   // (2,) f32
    float* out = (float*)d_out;                     // (N, C) f32

    int n = in_sizes[0] / 2;
    if (n <= 0) return;

    // Adaptive bin capacity from workspace: layout = cursor[KBINS] (16 KB)
    // then recIdx/recX/recY each [KBINS*cap].
    size_t curBytes = (size_t)KBINS * sizeof(unsigned);
    unsigned mean = (unsigned)(((unsigned long long)n + KBINS - 1) / KBINS);
    unsigned want = mean + mean / 32 + 64;   // ~+3% + 64 (>1.5 sigma at n=4M)
    size_t capAvail = (ws_size > curBytes)
                    ? (ws_size - curBytes) / ((size_t)KBINS * 12u) : 0;
    unsigned cap = capAvail < (size_t)want ? (unsigned)capAvail : want;

    if (cap < mean + 16) {
        // Workspace too small for useful binning: single-pass kernel.
        long long threads = 2LL * n;
        long long grid = (threads + 255) / 256;
        idx2pixel_simple<<<(int)grid, 256, 0, stream>>>(coords, visible, bias, out, n);
        return;
    }

    unsigned* cursor = (unsigned*)d_ws;
    unsigned* recIdx = (unsigned*)((char*)d_ws + curBytes);
    float* recX = (float*)(recIdx + (size_t)KBINS * cap);
    float* recY = recX + (size_t)KBINS * cap;

    hipMemsetAsync(cursor, 0, curBytes, stream);

    int sblocks = (int)(((long long)n + SBLOCK * SPT - 1) / (SBLOCK * SPT));
    scatter_kernel<<<sblocks, SBLOCK, 0, stream>>>(
        coords, visible, bias, out, cursor, recIdx, recX, recY, n, cap);

    gather_tile_kernel<<<KBINS, GBLOCK, 0, stream>>>(
        bias, visible, cursor, recIdx, recX, recY, out, cap);
}

// Round 7
// 479.886 us; speedup vs baseline: 1.1314x; 1.1314x over previous
//
#include <hip/hip_runtime.h>

#define IMG_H  2048
#define IMG_W  2048
#define IMG_C  8
#define IMG_WF (IMG_W * IMG_C)          // floats per image row = 16384

#define TILE   32                       // 32x32-pixel tiles
#define TB     (IMG_H / TILE)           // 64 tiles per dim
#define KBINS  (TB * TB)                // 4096 bins
#define TLR    (TILE + 1)               // 33 tile rows (halo)
#define TLC    ((TILE + 1) * IMG_C)     // 264 floats per tile row (halo col)
#define TLF4   (TLR * (TLC / 4))       // 2178 float4 per tile

#define SBLOCK 512
#define SPT    64                       // 32768 samples per scatter block
#define GBLOCK 256

// 12-byte AoS record: one contiguous write per sample (kills the 8x
// write amplification measured with 3 parallel SoA arrays in R6).
struct Rec { unsigned s; float x; float y; };

// ---------------------------------------------------------------------------
// Interp math, must match reference op order exactly:
//   c = max(coord - bias, 0); low = min(floor(c), H-2); d = c - low
//   mb = br + d0*(bl-br); mt = tr + d0*(tl-tr); out = mb + d1*(mt-mb)
// ---------------------------------------------------------------------------
__device__ __forceinline__ float4 lerp4(float4 tl, float4 tr, float4 bl, float4 br,
                                        float d0, float d1) {
    float4 o;
    float mb, mt;
    mb = br.x + d0 * (bl.x - br.x); mt = tr.x + d0 * (tl.x - tr.x); o.x = mb + d1 * (mt - mb);
    mb = br.y + d0 * (bl.y - br.y); mt = tr.y + d0 * (tl.y - tr.y); o.y = mb + d1 * (mt - mb);
    mb = br.z + d0 * (bl.z - br.z); mt = tr.z + d0 * (tl.z - tr.z); o.z = mb + d1 * (mt - mb);
    mb = br.w + d0 * (bl.w - br.w); mt = tr.w + d0 * (tl.w - tr.w); o.w = mb + d1 * (mt - mb);
    return o;
}

// 2D tile bin. Same clamp math as the interp -> scatter and gather derive
// bit-identical (i0,i1) from the stored coords.
__device__ __forceinline__ int bin2d(float cx, float cy, float b0, float b1) {
    float c0 = fmaxf(cx - b0, 0.0f);
    float c1 = fmaxf(cy - b1, 0.0f);
    float low0 = fminf(floorf(c0), (float)(IMG_H - 2));
    float low1 = fminf(floorf(c1), (float)(IMG_W - 2));
    return ((int)low0 >> 5) * TB + ((int)low1 >> 5);
}

// ---------------------------------------------------------------------------
// Pass 1: bin samples by 32x32 tile. LDS histogram -> chunk reservation
// (1 global atomic per bin per block) -> AoS record scatter. Phase 3
// increments basev[] directly (no third LDS array): LDS 32 KB -> 4
// blocks/CU at 512 threads (full 2048-thread residency; R6 was 19.8%).
// Overflow (>cap) is computed directly -> correctness never depends on cap.
// ---------------------------------------------------------------------------
__global__ __launch_bounds__(SBLOCK) void scatter_kernel(
    const float* __restrict__ coords,
    const float* __restrict__ visible,
    const float* __restrict__ bias,
    float* __restrict__ out,
    unsigned* __restrict__ cursor,     // [KBINS]
    Rec* __restrict__ rec,             // [KBINS*cap]
    int n, unsigned cap)
{
    __shared__ unsigned hist[KBINS];   // 16 KB
    __shared__ unsigned basev[KBINS];  // 16 KB (doubles as running slot ptr)

    int t = threadIdx.x;
    for (int u = t; u < KBINS; u += SBLOCK) hist[u] = 0;
    __syncthreads();

    int blockStart = blockIdx.x * (SBLOCK * SPT);
    float b0 = bias[0];
    float b1 = bias[1];

    // phase 1: LDS histogram (coalesced coords reads)
    for (int k = 0; k < SPT; ++k) {
        int s = blockStart + k * SBLOCK + t;
        if (s < n) {
            float2 cv = *(const float2*)(coords + 2 * (size_t)s);
            atomicAdd(&hist[bin2d(cv.x, cv.y, b0, b1)], 1u);
        }
    }
    __syncthreads();

    // phase 2: reserve a contiguous chunk per bin
    for (int u = t; u < KBINS; u += SBLOCK) {
        unsigned h = hist[u];
        basev[u] = h ? atomicAdd(&cursor[u], h) : 0u;
    }
    __syncthreads();

    // phase 3: scatter AoS records (coords re-read, L2-hot)
    for (int k = 0; k < SPT; ++k) {
        int s = blockStart + k * SBLOCK + t;
        if (s < n) {
            float2 cv = *(const float2*)(coords + 2 * (size_t)s);
            int b = bin2d(cv.x, cv.y, b0, b1);
            unsigned slot = atomicAdd(&basev[b], 1u);
            if (slot < cap) {
                Rec r; r.s = (unsigned)s; r.x = cv.x; r.y = cv.y;
                rec[(size_t)b * cap + slot] = r;
            } else {
                // Overflow: compute this sample directly (rare).
                float c0 = fmaxf(cv.x - b0, 0.0f);
                float c1 = fmaxf(cv.y - b1, 0.0f);
                float low0 = fminf(floorf(c0), (float)(IMG_H - 2));
                float low1 = fminf(floorf(c1), (float)(IMG_W - 2));
                float d0 = c0 - low0;
                float d1 = c1 - low1;
                int i0 = (int)low0;
                int i1 = (int)low1;
                const float* pt = visible + ((size_t)i0 * IMG_W + (size_t)i1) * IMG_C;
                const float* pb = pt + (size_t)IMG_W * IMG_C;
                for (int q = 0; q < 2; ++q) {
                    float4 tl = *(const float4*)(pt + 4 * q);
                    float4 bl = *(const float4*)(pt + 8 + 4 * q);
                    float4 tr = *(const float4*)(pb + 4 * q);
                    float4 br = *(const float4*)(pb + 8 + 4 * q);
                    float4 o = lerp4(tl, tr, bl, br, d0, d1);
                    *(float4*)(out + (size_t)s * IMG_C + 4 * q) = o;
                }
            }
        }
    }
}

// ---------------------------------------------------------------------------
// Pass 2: one block per tile-bin. Stage the 33x33-pixel tile (34.8 KB) in
// LDS -- each visible byte read from HBM exactly once, immune to cache
// eviction -- then serve the bin's samples from LDS. One thread per sample.
// ---------------------------------------------------------------------------
__global__ __launch_bounds__(GBLOCK) void gather_tile_kernel(
    const float* __restrict__ bias,
    const float* __restrict__ visible,
    const unsigned* __restrict__ cursor,   // fill counts per bin
    const Rec* __restrict__ rec,
    float* __restrict__ out,
    unsigned cap)
{
    __shared__ float tile[TLR * TLC];      // 34848 B

    int b  = blockIdx.x;                   // bin id 0..4095
    int bh = b >> 6;                       // tile row
    int bw = b & (TB - 1);                 // tile col
    int r0  = bh * TILE;
    int c0f = bw * TILE * IMG_C;

    int t = threadIdx.x;

    // Stage tile + halo (clamped cells are never read: i0<=H-2 -> lr<=31).
    for (int v = t; v < TLF4; v += GBLOCK) {
        int trow = v / (TLC / 4);          // 0..32
        int tc4  = v - trow * (TLC / 4);   // 0..65
        int gr = r0 + trow;  if (gr > IMG_H - 1) gr = IMG_H - 1;
        int gf = c0f + tc4 * 4; if (gf > IMG_WF - 4) gf = IMG_WF - 4;
        *(float4*)(&tile[trow * TLC + tc4 * 4]) =
            *(const float4*)(visible + (size_t)gr * IMG_WF + gf);
    }
    __syncthreads();

    float b0 = bias[0];
    float b1 = bias[1];

    unsigned cnt = cursor[b];
    if (cnt > cap) cnt = cap;
    size_t base = (size_t)b * cap;

    for (unsigned j = t; j < cnt; j += GBLOCK) {
        Rec r = rec[base + j];

        float cc0 = fmaxf(r.x - b0, 0.0f);
        float cc1 = fmaxf(r.y - b1, 0.0f);
        float low0 = fminf(floorf(cc0), (float)(IMG_H - 2));
        float low1 = fminf(floorf(cc1), (float)(IMG_W - 2));
        float d0 = cc0 - low0;
        float d1 = cc1 - low1;
        int lr  = (int)low0 - r0;                // 0..31 by bin construction
        int lcf = (int)low1 * IMG_C - c0f;       // 0..248

        const float* q_t = &tile[lr * TLC + lcf];
        const float* q_b = q_t + TLC;

        float4 tl0 = *(const float4*)(q_t);
        float4 bl0 = *(const float4*)(q_t + IMG_C);
        float4 tr0 = *(const float4*)(q_b);
        float4 br0 = *(const float4*)(q_b + IMG_C);
        float4 o0 = lerp4(tl0, tr0, bl0, br0, d0, d1);

        float4 tl1 = *(const float4*)(q_t + 4);
        float4 bl1 = *(const float4*)(q_t + IMG_C + 4);
        float4 tr1 = *(const float4*)(q_b + 4);
        float4 br1 = *(const float4*)(q_b + IMG_C + 4);
        float4 o1 = lerp4(tl1, tr1, bl1, br1, d0, d1);

        *(float4*)(out + (size_t)r.s * IMG_C)     = o0;
        *(float4*)(out + (size_t)r.s * IMG_C + 4) = o1;
    }
}

// ---------------------------------------------------------------------------
// Fallback (ws too small): proven single-pass kernel (R0/R2, 228 us).
// ---------------------------------------------------------------------------
__global__ __launch_bounds__(256) void idx2pixel_simple(
    const float* __restrict__ coords,
    const float* __restrict__ visible,
    const float* __restrict__ bias,
    float* __restrict__ out,
    int n)
{
    int tid = blockIdx.x * blockDim.x + threadIdx.x;
    int s = tid >> 1;
    int part = tid & 1;
    if (s >= n) return;

    float2 cv = *(const float2*)(coords + 2 * (size_t)s);
    float b0 = bias[0];
    float b1 = bias[1];

    float c0 = fmaxf(cv.x - b0, 0.0f);
    float c1 = fmaxf(cv.y - b1, 0.0f);
    float low0 = fminf(floorf(c0), (float)(IMG_H - 2));
    float low1 = fminf(floorf(c1), (float)(IMG_W - 2));
    float d0 = c0 - low0;
    float d1 = c1 - low1;
    int i0 = (int)low0;
    int i1 = (int)low1;

    const float* p_t = visible + ((size_t)i0 * IMG_W + (size_t)i1) * IMG_C + part * 4;
    const float* p_b = p_t + (size_t)IMG_W * IMG_C;

    float4 tl = *(const float4*)(p_t);
    float4 bl = *(const float4*)(p_t + 8);
    float4 tr = *(const float4*)(p_b);
    float4 br = *(const float4*)(p_b + 8);

    float4 o = lerp4(tl, tr, bl, br, d0, d1);
    *(float4*)(out + (size_t)s * IMG_C + part * 4) = o;
}

extern "C" void kernel_launch(void* const* d_in, const int* in_sizes, int n_in,
                              void* d_out, int out_size, void* d_ws, size_t ws_size,
                              hipStream_t stream) {
    const float* coords  = (const float*)d_in[0];   // (N, 2) f32
    const float* visible = (const float*)d_in[1];   // (H, W, C) f32
    const float* bias    = (const float*)d_in[2];   // (2,) f32
    float* out = (float*)d_out;                     // (N, C) f32

    int n = in_sizes[0] / 2;
    if (n <= 0) return;

    // Workspace layout: cursor[KBINS] (16 KB) then rec[KBINS*cap] (12 B each).
    size_t curBytes = (size_t)KBINS * sizeof(unsigned);
    unsigned mean = (unsigned)(((unsigned long long)n + KBINS - 1) / KBINS);
    unsigned want = mean + mean / 32 + 64;   // ~+3% + 64 slack
    size_t capAvail = (ws_size > curBytes)
                    ? (ws_size - curBytes) / ((size_t)KBINS * sizeof(Rec)) : 0;
    unsigned cap = capAvail < (size_t)want ? (unsigned)capAvail : want;

    if (cap < mean + 16) {
        long long threads = 2LL * n;
        long long grid = (threads + 255) / 256;
        idx2pixel_simple<<<(int)grid, 256, 0, stream>>>(coords, visible, bias, out, n);
        return;
    }

    unsigned* cursor = (unsigned*)d_ws;
    Rec* rec = (Rec*)((char*)d_ws + curBytes);

    hipMemsetAsync(cursor, 0, curBytes, stream);

    int sblocks = (int)(((long long)n + SBLOCK * SPT - 1) / (SBLOCK * SPT));
    scatter_kernel<<<sblocks, SBLOCK, 0, stream>>>(
        coords, visible, bias, out, cursor, rec, n, cap);

    gather_tile_kernel<<<KBINS, GBLOCK, 0, stream>>>(
        bias, visible, cursor, rec, out, cap);
}

// Round 8
// 452.027 us; speedup vs baseline: 1.2011x; 1.0616x over previous
//
#include <hip/hip_runtime.h>

#define IMG_H  2048
#define IMG_W  2048
#define IMG_C  8
#define IMG_WF (IMG_W * IMG_C)          // floats per image row = 16384

#define TILE   32                       // 32x32-pixel tiles
#define TB     (IMG_H / TILE)           // 64 tiles per dim
#define KBINS  (TB * TB)                // 4096 bins
#define TLR    (TILE + 1)               // 33 tile rows (halo)
#define TLC    ((TILE + 1) * IMG_C)     // 264 floats of payload per tile row
#define TSTRIDE 268                     // padded stride: 67 float4 -> row bank
                                        // shift = 3 (odd) -> ds_read_b128 start
                                        // = (2*lc+3*lr)%8 covers ALL 8 float4
                                        // bank positions (264 gave only 4 ->
                                        // 6.6M conflicts measured in R7)
#define TLF4   (TLR * (TLC / 4))        // 2178 payload float4 per tile

#define SBLOCK 512
#define SPT    32                       // 16384 samples/block -> 256 blocks (1/CU)
#define GBLOCK 256

// 12-byte AoS record: one contiguous write per sample.
struct Rec { unsigned s; float x; float y; };

// ---------------------------------------------------------------------------
// Interp math, must match reference op order exactly:
//   c = max(coord - bias, 0); low = min(floor(c), H-2); d = c - low
//   mb = br + d0*(bl-br); mt = tr + d0*(tl-tr); out = mb + d1*(mt-mb)
// ---------------------------------------------------------------------------
__device__ __forceinline__ float4 lerp4(float4 tl, float4 tr, float4 bl, float4 br,
                                        float d0, float d1) {
    float4 o;
    float mb, mt;
    mb = br.x + d0 * (bl.x - br.x); mt = tr.x + d0 * (tl.x - tr.x); o.x = mb + d1 * (mt - mb);
    mb = br.y + d0 * (bl.y - br.y); mt = tr.y + d0 * (tl.y - tr.y); o.y = mb + d1 * (mt - mb);
    mb = br.z + d0 * (bl.z - br.z); mt = tr.z + d0 * (tl.z - tr.z); o.z = mb + d1 * (mt - mb);
    mb = br.w + d0 * (bl.w - br.w); mt = tr.w + d0 * (tl.w - tr.w); o.w = mb + d1 * (mt - mb);
    return o;
}

// 2D tile bin. Same clamp math as the interp -> scatter and gather derive
// bit-identical (i0,i1) from the stored coords.
__device__ __forceinline__ int bin2d(float cx, float cy, float b0, float b1) {
    float c0 = fmaxf(cx - b0, 0.0f);
    float c1 = fmaxf(cy - b1, 0.0f);
    float low0 = fminf(floorf(c0), (float)(IMG_H - 2));
    float low1 = fminf(floorf(c1), (float)(IMG_W - 2));
    return ((int)low0 >> 5) * TB + ((int)low1 >> 5);
}

// ---------------------------------------------------------------------------
// Pass 1: bin samples by 32x32 tile. 256 blocks (R7 had 128 -> half the GPU
// idle). ONE 16 KB LDS array serves as histogram, then per-bin base, then
// running slot pointer (count -> convert in place -> bump). Overflow (>cap)
// is computed directly -> correctness never depends on capacity.
// ---------------------------------------------------------------------------
__global__ __launch_bounds__(SBLOCK) void scatter_kernel(
    const float* __restrict__ coords,
    const float* __restrict__ visible,
    const float* __restrict__ bias,
    float* __restrict__ out,
    unsigned* __restrict__ cursor,     // [KBINS]
    Rec* __restrict__ rec,             // [KBINS*cap]
    int n, unsigned cap)
{
    __shared__ unsigned hist[KBINS];   // 16 KB total LDS

    int t = threadIdx.x;
    for (int u = t; u < KBINS; u += SBLOCK) hist[u] = 0;
    __syncthreads();

    int blockStart = blockIdx.x * (SBLOCK * SPT);
    float b0 = bias[0];
    float b1 = bias[1];

    // phase 1: LDS histogram (coalesced coords reads)
    for (int k = 0; k < SPT; ++k) {
        int s = blockStart + k * SBLOCK + t;
        if (s < n) {
            float2 cv = *(const float2*)(coords + 2 * (size_t)s);
            atomicAdd(&hist[bin2d(cv.x, cv.y, b0, b1)], 1u);
        }
    }
    __syncthreads();

    // phase 2: convert count -> global base, in place
    for (int u = t; u < KBINS; u += SBLOCK) {
        unsigned h = hist[u];
        hist[u] = h ? atomicAdd(&cursor[u], h) : 0u;
    }
    __syncthreads();

    // phase 3: scatter AoS records (coords re-read, L2-hot; R7 FETCH showed
    // the re-read is fully cached)
    for (int k = 0; k < SPT; ++k) {
        int s = blockStart + k * SBLOCK + t;
        if (s < n) {
            float2 cv = *(const float2*)(coords + 2 * (size_t)s);
            int b = bin2d(cv.x, cv.y, b0, b1);
            unsigned slot = atomicAdd(&hist[b], 1u);
            if (slot < cap) {
                Rec r; r.s = (unsigned)s; r.x = cv.x; r.y = cv.y;
                rec[(size_t)b * cap + slot] = r;
            } else {
                // Overflow: compute this sample directly (rare).
                float c0 = fmaxf(cv.x - b0, 0.0f);
                float c1 = fmaxf(cv.y - b1, 0.0f);
                float low0 = fminf(floorf(c0), (float)(IMG_H - 2));
                float low1 = fminf(floorf(c1), (float)(IMG_W - 2));
                float d0 = c0 - low0;
                float d1 = c1 - low1;
                int i0 = (int)low0;
                int i1 = (int)low1;
                const float* pt = visible + ((size_t)i0 * IMG_W + (size_t)i1) * IMG_C;
                const float* pb = pt + (size_t)IMG_W * IMG_C;
                for (int q = 0; q < 2; ++q) {
                    float4 tl = *(const float4*)(pt + 4 * q);
                    float4 bl = *(const float4*)(pt + 8 + 4 * q);
                    float4 tr = *(const float4*)(pb + 4 * q);
                    float4 br = *(const float4*)(pb + 8 + 4 * q);
                    float4 o = lerp4(tl, tr, bl, br, d0, d1);
                    *(float4*)(out + (size_t)s * IMG_C + 4 * q) = o;
                }
            }
        }
    }
}

// ---------------------------------------------------------------------------
// Pass 2: one block per tile-bin. Stage the 33x33-pixel tile in LDS (each
// visible byte read from HBM exactly once, immune to cache eviction), then
// serve the bin's samples from LDS. Padded stride kills the R7 16-way bank
// conflict. One thread per sample (all 8 channels).
// ---------------------------------------------------------------------------
__global__ __launch_bounds__(GBLOCK) void gather_tile_kernel(
    const float* __restrict__ bias,
    const float* __restrict__ visible,
    const unsigned* __restrict__ cursor,   // fill counts per bin
    const Rec* __restrict__ rec,
    float* __restrict__ out,
    unsigned cap)
{
    __shared__ float tile[TLR * TSTRIDE];  // 33*268*4 = 35376 B

    int b  = blockIdx.x;                   // bin id 0..4095
    int bh = b >> 6;                       // tile row
    int bw = b & (TB - 1);                 // tile col
    int r0  = bh * TILE;
    int c0f = bw * TILE * IMG_C;

    int t = threadIdx.x;

    // Stage tile + halo (clamped cells are never read: i0<=H-2 -> lr+1<=32,
    // i1<=W-2 -> lc+1<=32 < 33 staged px).
    for (int v = t; v < TLF4; v += GBLOCK) {
        int trow = v / (TLC / 4);          // 0..32
        int tc4  = v - trow * (TLC / 4);   // 0..65
        int gr = r0 + trow;  if (gr > IMG_H - 1) gr = IMG_H - 1;
        int gf = c0f + tc4 * 4; if (gf > IMG_WF - 4) gf = IMG_WF - 4;
        *(float4*)(&tile[trow * TSTRIDE + tc4 * 4]) =
            *(const float4*)(visible + (size_t)gr * IMG_WF + gf);
    }
    __syncthreads();

    float b0 = bias[0];
    float b1 = bias[1];

    unsigned cnt = cursor[b];
    if (cnt > cap) cnt = cap;
    size_t base = (size_t)b * cap;

    for (unsigned j = t; j < cnt; j += GBLOCK) {
        Rec r = rec[base + j];

        float cc0 = fmaxf(r.x - b0, 0.0f);
        float cc1 = fmaxf(r.y - b1, 0.0f);
        float low0 = fminf(floorf(cc0), (float)(IMG_H - 2));
        float low1 = fminf(floorf(cc1), (float)(IMG_W - 2));
        float d0 = cc0 - low0;
        float d1 = cc1 - low1;
        int lr  = (int)low0 - r0;                // 0..31 by bin construction
        int lcf = ((int)low1 * IMG_C - c0f);     // 0..248

        const float* q_t = &tile[lr * TSTRIDE + lcf];
        const float* q_b = q_t + TSTRIDE;

        float4 tl0 = *(const float4*)(q_t);
        float4 bl0 = *(const float4*)(q_t + IMG_C);
        float4 tr0 = *(const float4*)(q_b);
        float4 br0 = *(const float4*)(q_b + IMG_C);
        float4 o0 = lerp4(tl0, tr0, bl0, br0, d0, d1);

        float4 tl1 = *(const float4*)(q_t + 4);
        float4 bl1 = *(const float4*)(q_t + IMG_C + 4);
        float4 tr1 = *(const float4*)(q_b + 4);
        float4 br1 = *(const float4*)(q_b + IMG_C + 4);
        float4 o1 = lerp4(tl1, tr1, bl1, br1, d0, d1);

        *(float4*)(out + (size_t)r.s * IMG_C)     = o0;
        *(float4*)(out + (size_t)r.s * IMG_C + 4) = o1;
    }
}

// ---------------------------------------------------------------------------
// Fallback (ws too small): proven single-pass kernel (R0/R2, 228 us).
// ---------------------------------------------------------------------------
__global__ __launch_bounds__(256) void idx2pixel_simple(
    const float* __restrict__ coords,
    const float* __restrict__ visible,
    const float* __restrict__ bias,
    float* __restrict__ out,
    int n)
{
    int tid = blockIdx.x * blockDim.x + threadIdx.x;
    int s = tid >> 1;
    int part = tid & 1;
    if (s >= n) return;

    float2 cv = *(const float2*)(coords + 2 * (size_t)s);
    float b0 = bias[0];
    float b1 = bias[1];

    float c0 = fmaxf(cv.x - b0, 0.0f);
    float c1 = fmaxf(cv.y - b1, 0.0f);
    float low0 = fminf(floorf(c0), (float)(IMG_H - 2));
    float low1 = fminf(floorf(c1), (float)(IMG_W - 2));
    float d0 = c0 - low0;
    float d1 = c1 - low1;
    int i0 = (int)low0;
    int i1 = (int)low1;

    const float* p_t = visible + ((size_t)i0 * IMG_W + (size_t)i1) * IMG_C + part * 4;
    const float* p_b = p_t + (size_t)IMG_W * IMG_C;

    float4 tl = *(const float4*)(p_t);
    float4 bl = *(const float4*)(p_t + 8);
    float4 tr = *(const float4*)(p_b);
    float4 br = *(const float4*)(p_b + 8);

    float4 o = lerp4(tl, tr, bl, br, d0, d1);
    *(float4*)(out + (size_t)s * IMG_C + part * 4) = o;
}

extern "C" void kernel_launch(void* const* d_in, const int* in_sizes, int n_in,
                              void* d_out, int out_size, void* d_ws, size_t ws_size,
                              hipStream_t stream) {
    const float* coords  = (const float*)d_in[0];   // (N, 2) f32
    const float* visible = (const float*)d_in[1];   // (H, W, C) f32
    const float* bias    = (const float*)d_in[2];   // (2,) f32
    float* out = (float*)d_out;                     // (N, C) f32

    int n = in_sizes[0] / 2;
    if (n <= 0) return;

    // Workspace layout: cursor[KBINS] (16 KB) then rec[KBINS*cap] (12 B each).
    size_t curBytes = (size_t)KBINS * sizeof(unsigned);
    unsigned mean = (unsigned)(((unsigned long long)n + KBINS - 1) / KBINS);
    unsigned want = mean + mean / 32 + 64;   // ~+3% + 64 slack (~3 sigma)
    size_t capAvail = (ws_size > curBytes)
                    ? (ws_size - curBytes) / ((size_t)KBINS * sizeof(Rec)) : 0;
    unsigned cap = capAvail < (size_t)want ? (unsigned)capAvail : want;

    if (cap < mean + 16) {
        long long threads = 2LL * n;
        long long grid = (threads + 255) / 256;
        idx2pixel_simple<<<(int)grid, 256, 0, stream>>>(coords, visible, bias, out, n);
        return;
    }

    unsigned* cursor = (unsigned*)d_ws;
    Rec* rec = (Rec*)((char*)d_ws + curBytes);

    hipMemsetAsync(cursor, 0, curBytes, stream);

    int sblocks = (int)(((long long)n + SBLOCK * SPT - 1) / (SBLOCK * SPT));
    scatter_kernel<<<sblocks, SBLOCK, 0, stream>>>(
        coords, visible, bias, out, cursor, rec, n, cap);

    gather_tile_kernel<<<KBINS, GBLOCK, 0, stream>>>(
        bias, visible, cursor, rec, out, cap);
}